// Round 6
// baseline (202.325 us; speedup 1.0000x reference)
//
#include <hip/hip_runtime.h>
#include <math.h>

constexpr int N  = 50000;
constexpr int E  = 400000;
constexpr int R  = 1000;
constexpr int K1 = 1000;
constexpr int F  = 128;
constexpr int OUTC = 256;
constexpr int P  = 64;

typedef _Float16 f16x8 __attribute__((ext_vector_type(8)));
typedef _Float16 f16x4 __attribute__((ext_vector_type(4)));
typedef _Float16 f16x2 __attribute__((ext_vector_type(2)));
typedef float f32x4 __attribute__((ext_vector_type(4)));

#if __has_builtin(__builtin_amdgcn_fdot2)
#define FDOT2(a, b, c) __builtin_amdgcn_fdot2((a), (b), (c), false)
#else
#define FDOT2(a, b, c) fmaf((float)(a)[0], (float)(b)[0], fmaf((float)(a)[1], (float)(b)[1], (c)))
#endif

__device__ inline float waveReduceSum(float v) {
#pragma unroll
    for (int m = 32; m >= 1; m >>= 1) v += __shfl_xor(v, m, 64);
    return v;
}

// ---------------- prep1: featsh | relprep | seg+edgepack | fragprep --------------
// B-frag 16x16x32: lane L holds B[k = kk*32 + (L>>4)*8 + j][n = base + (L&15)]
constexpr int B_FEATSH = 6250;   // N*F/4 / 256
constexpr int B_REL    = 250;    // R/4 (wave per relation)
constexpr int B_SEG    = 1563;
constexpr int B_FRAG   = 56;     // 224 64-thread units / 4

__global__ __launch_bounds__(256) void prep1(
        const float* __restrict__ feats, const float* __restrict__ rel_emb,
        const float* __restrict__ attn,  const float* __restrict__ proxy,
        const float* __restrict__ G,     const int* __restrict__ adj,
        const int* __restrict__ sidx,    const float* __restrict__ val,
        _Float16* __restrict__ featsH,   _Float16* __restrict__ relnormH,
        float* __restrict__ dotr, int* __restrict__ nstart, int* __restrict__ nend,
        int4* __restrict__ epack,
        f16x8* __restrict__ Gh, f16x8* __restrict__ pnH,
        f16x8* __restrict__ pxH, f16x8* __restrict__ pgH) {
    int b = blockIdx.x, tid = threadIdx.x;
    if (b < B_FEATSH) {
        int idx = b * 256 + tid;
        float4 x = ((const float4*)feats)[idx];
        f16x4 h;
        h[0] = (_Float16)x.x; h[1] = (_Float16)x.y;
        h[2] = (_Float16)x.z; h[3] = (_Float16)x.w;
        ((f16x4*)featsH)[idx] = h;
    } else if (b < B_FEATSH + B_REL) {
        int r = (b - B_FEATSH) * 4 + (tid >> 6);
        int lane = tid & 63;
        float2 v  = ((const float2*)(rel_emb + (size_t)r * F))[lane];
        float2 a0 = ((const float2*)attn)[lane];
        float2 a1 = ((const float2*)attn)[64 + lane];
        float ss = waveReduceSum(v.x * v.x + v.y * v.y);
        float d0 = waveReduceSum(v.x * a0.x + v.y * a0.y);
        float d1 = waveReduceSum(v.x * a1.x + v.y * a1.y);
        float sc = rsqrtf(fmaxf(ss, 1e-12f));
        f16x2 h; h[0] = (_Float16)(v.x * sc); h[1] = (_Float16)(v.y * sc);
        ((f16x2*)(relnormH + (size_t)r * F))[lane] = h;
        if (lane == 0) { dotr[2 * r] = d0; dotr[2 * r + 1] = d1; }
    } else if (b < B_FEATSH + B_REL + B_SEG) {
        int e = (b - B_FEATSH - B_REL) * 256 + tid;
        if (e < E) {
            int2 a2 = ((const int2*)adj)[e];
            int row = a2.x;
            int rel = ((const int2*)sidx)[e].y;
            epack[e] = make_int4(a2.y, rel, __float_as_int(val[e]), 0);
            int prev = (e > 0) ? ((const int2*)adj)[e - 1].x : -1;
            if (prev != row) {
                nstart[row] = e;
                for (int rr = prev + 1; rr < row; ++rr) { nstart[rr] = e; nend[rr] = e; }
            }
            if (e == E - 1) {
                nend[row] = E;
                for (int rr = row + 1; rr < N; ++rr) { nstart[rr] = E; nend[rr] = E; }
            } else if (((const int2*)adj)[e + 1].x != row) {
                nend[row] = e + 1;
            }
        }
    } else {
        int u = (b - B_FEATSH - B_REL - B_SEG) * 4 + (tid >> 6);  // 0..223
        int L = tid & 63;
        int q = L >> 4, m = L & 15;
        f16x8 h;
        if (u < 128) {                               // Gh: G (256x256)
            int kk = u >> 4, cg = u & 15;
            int n = cg * 16 + m;
#pragma unroll
            for (int j = 0; j < 8; ++j)
                h[j] = (_Float16)G[(size_t)(kk * 32 + q * 8 + j) * OUTC + n];
            Gh[(size_t)u * 64 + L] = h;
        } else if (u < 160) {                        // pnH: l2n(proxy)^T (256x64)
            int idx = u - 128;
            int kk = idx >> 2, w = idx & 3;
            int n = w * 16 + m;
            float ssum = 0.f;
            for (int k = 0; k < OUTC; ++k) {
                float pv = proxy[(size_t)n * OUTC + k];
                ssum = fmaf(pv, pv, ssum);
            }
            float sc = rsqrtf(fmaxf(ssum, 1e-12f));
#pragma unroll
            for (int j = 0; j < 8; ++j)
                h[j] = (_Float16)(proxy[(size_t)n * OUTC + kk * 32 + q * 8 + j] * sc);
            pnH[(size_t)idx * 64 + L] = h;
        } else if (u < 192) {                        // pxH: proxy (64x256)
            int idx = u - 160;
            int kk = idx >> 4, cg = idx & 15;
            int n = cg * 16 + m;
#pragma unroll
            for (int j = 0; j < 8; ++j)
                h[j] = (_Float16)proxy[(size_t)(kk * 32 + q * 8 + j) * OUTC + n];
            pxH[(size_t)idx * 64 + L] = h;
        } else {                                     // pgH: -(proxy@G) on the fly
            int idx = u - 192;
            int kk = idx >> 4, cg = idx & 15;
            int n = cg * 16 + m;
#pragma unroll
            for (int j = 0; j < 8; ++j) {
                int p = kk * 32 + q * 8 + j;
                float s = 0.f;
                for (int k = 0; k < OUTC; ++k)
                    s = fmaf(proxy[(size_t)p * OUTC + k], G[(size_t)k * OUTC + n], s);
                h[j] = (_Float16)(-s);
            }
            pgH[(size_t)idx * 64 + L] = h;
        }
    }
}

// ---------------- C: single-pass aggregation (normalize at end) ------------------
__global__ __launch_bounds__(256) void node_aggregate(
        const _Float16* __restrict__ featsH,
        const _Float16* __restrict__ relnormH,
        const float* __restrict__ dotr,
        const int4* __restrict__ epack,
        const int* __restrict__ nstart,
        const int* __restrict__ nend,
        _Float16* __restrict__ nf0,
        _Float16* __restrict__ nf1) {
    int n = blockIdx.x * 4 + (threadIdx.x >> 6);
    int lane = threadIdx.x & 63;
    int g = lane >> 4, gl = lane & 15;
    int start = nstart[n], end = nend[n];
    float A0[8], A1[8];
#pragma unroll
    for (int j = 0; j < 8; ++j) { A0[j] = 0.f; A1[j] = 0.f; }
    float s0 = 0.f, s1 = 0.f;
    for (int e = start + g; e < end; e += 8) {
        int eB = e + 4;
        bool hasB = (eB < end);
        int eBc = hasB ? eB : e;
        int4 mA = epack[e], mB = epack[eBc];
        float2 drA = ((const float2*)dotr)[mA.y];
        float2 drB = ((const float2*)dotr)[mB.y];
        float vA = __int_as_float(mA.z), vB = __int_as_float(mB.z);
        float wA0 = __expf(vA * drA.x), wA1 = __expf(vA * drA.y);
        float wB0 = hasB ? __expf(vB * drB.x) : 0.f;
        float wB1 = hasB ? __expf(vB * drB.y) : 0.f;
        s0 += wA0 + wB0; s1 += wA1 + wB1;
        f16x8 fAv = ((const f16x8*)(featsH   + (size_t)mA.x * F))[gl];
        f16x8 rAv = ((const f16x8*)(relnormH + (size_t)mA.y * F))[gl];
        f16x8 fBv = ((const f16x8*)(featsH   + (size_t)mB.x * F))[gl];
        f16x8 rBv = ((const f16x8*)(relnormH + (size_t)mB.y * F))[gl];
        const f16x2* fA2 = (const f16x2*)&fAv;
        const f16x2* rA2 = (const f16x2*)&rAv;
        const f16x2* fB2 = (const f16x2*)&fBv;
        const f16x2* rB2 = (const f16x2*)&rBv;
        float pdA = 0.f, pdB = 0.f;
#pragma unroll
        for (int j = 0; j < 4; ++j) {
            pdA = FDOT2(fA2[j], rA2[j], pdA);
            pdB = FDOT2(fB2[j], rB2[j], pdB);
        }
        pdA += __shfl_xor(pdA, 1, 64); pdB += __shfl_xor(pdB, 1, 64);
        pdA += __shfl_xor(pdA, 2, 64); pdB += __shfl_xor(pdB, 2, 64);
        pdA += __shfl_xor(pdA, 4, 64); pdB += __shfl_xor(pdB, 4, 64);
        pdA += __shfl_xor(pdA, 8, 64); pdB += __shfl_xor(pdB, 8, 64);
        _Float16 tAh = (_Float16)(2.f * pdA), tBh = (_Float16)(2.f * pdB);
        f16x2 tA2; tA2[0] = tAh; tA2[1] = tAh;
        f16x2 tB2; tB2[0] = tBh; tB2[1] = tBh;
#pragma unroll
        for (int j = 0; j < 4; ++j) {
            f16x2 rxA = fA2[j] - tA2 * rA2[j];
            f16x2 rxB = fB2[j] - tB2 * rB2[j];
            float x0 = (float)rxA[0], x1 = (float)rxA[1];
            float y0 = (float)rxB[0], y1 = (float)rxB[1];
            A0[2*j]   = fmaf(wA0, x0, A0[2*j]);   A0[2*j]   = fmaf(wB0, y0, A0[2*j]);
            A0[2*j+1] = fmaf(wA0, x1, A0[2*j+1]); A0[2*j+1] = fmaf(wB0, y1, A0[2*j+1]);
            A1[2*j]   = fmaf(wA1, x0, A1[2*j]);   A1[2*j]   = fmaf(wB1, y0, A1[2*j]);
            A1[2*j+1] = fmaf(wA1, x1, A1[2*j+1]); A1[2*j+1] = fmaf(wB1, y1, A1[2*j+1]);
        }
    }
#pragma unroll
    for (int j = 0; j < 8; ++j) {
        A0[j] += __shfl_xor(A0[j], 16, 64); A0[j] += __shfl_xor(A0[j], 32, 64);
        A1[j] += __shfl_xor(A1[j], 16, 64); A1[j] += __shfl_xor(A1[j], 32, 64);
    }
    s0 += __shfl_xor(s0, 16, 64); s0 += __shfl_xor(s0, 32, 64);
    s1 += __shfl_xor(s1, 16, 64); s1 += __shfl_xor(s1, 32, 64);
    float i0 = (s0 > 0.f) ? 1.f / s0 : 0.f;
    float i1 = (s1 > 0.f) ? 1.f / s1 : 0.f;
    if (g == 0) {
        f16x8 h0, h1;
#pragma unroll
        for (int j = 0; j < 8; ++j) {
            h0[j] = (_Float16)(A0[j] * i0);
            h1[j] = (_Float16)(A1[j] * i1);
        }
        ((f16x8*)(nf0 + (size_t)n * F))[gl] = h0;
        ((f16x8*)(nf1 + (size_t)n * F))[gl] = h1;
    }
}

// ---------------- F: fused build + proxy attention + gate, 64 rows/block ----------
// z = out@G - att@(proxy@G);  q = att@proxy;  final = out - (1-sigmoid(z))*q
constexpr int RT = 4;   // 16-row tiles per block
__global__ __launch_bounds__(256, 2) void proxy_gate(
        const _Float16* __restrict__ featsH,
        const _Float16* __restrict__ nf0,
        const _Float16* __restrict__ nf1,
        const int* __restrict__ neigh,
        const f16x8* __restrict__ pnH,
        const f16x8* __restrict__ pxH,
        const f16x8* __restrict__ Gh,
        const f16x8* __restrict__ pgH,
        float* __restrict__ out) {
    constexpr int LDA = 68;
    __shared__ __align__(16) f16x8 outH[RT * 8 * 64];     // 32 KB, A-frag order
    __shared__ __align__(16) float attL[RT * 16 * LDA];   // 17.4 KB
    __shared__ float scaleL[RT * 16];
    int tid = threadIdx.x;
    int w = tid >> 6, lane = tid & 63;
    int quad = lane >> 4, m = lane & 15;
    size_t row0 = (size_t)blockIdx.x * (RT * 16);

    // ---- build tiles -> f16 A-frags + row 1/norm ----
    {
        int bm = tid >> 4, gl = tid & 15;
#pragma unroll
        for (int t = 0; t < RT; ++t) {
            int n = (int)row0 + t * 16 + bm;
            float ss;
            f16x8 h1, h2;
            if (n < N) {
                ss = 0.f;
                h1 = ((const f16x8*)(featsH + (size_t)n * F))[gl];
#pragma unroll
                for (int j = 0; j < 8; ++j) { float x = (float)h1[j]; ss += x * x; }
                int sel = (n < K1) ? neigh[n] : n;
                f16x8 a  = ((const f16x8*)(nf0 + (size_t)n   * F))[gl];
                f16x8 b2 = ((const f16x8*)(nf1 + (size_t)sel * F))[gl];
#pragma unroll
                for (int j = 0; j < 8; ++j) {
                    float v = 0.5f * ((float)a[j] + (float)b2[j]);
                    h2[j] = (_Float16)v;
                    ss += v * v;
                }
            } else {
#pragma unroll
                for (int j = 0; j < 8; ++j) { h1[j] = (_Float16)0.f; h2[j] = (_Float16)0.f; }
                ss = 1.f;
            }
            outH[(t * 8 +     (gl >> 2)) * 64 + (gl & 3) * 16 + bm] = h1;
            outH[(t * 8 + 4 + (gl >> 2)) * 64 + (gl & 3) * 16 + bm] = h2;
            ss += __shfl_xor(ss, 1, 64); ss += __shfl_xor(ss, 2, 64);
            ss += __shfl_xor(ss, 4, 64); ss += __shfl_xor(ss, 8, 64);
            if (gl == 0) scaleL[t * 16 + bm] = rsqrtf(fmaxf(ss, 1e-12f));
        }
    }
    __syncthreads();

    // ---- logits (wave w: proxies 16w..) + z partial = out@G (cols cg=w+4i) ----
    f32x4 lacc[RT];
    f32x4 zacc[RT][4];
#pragma unroll
    for (int t = 0; t < RT; ++t) {
        lacc[t] = (f32x4){0,0,0,0};
#pragma unroll
        for (int c = 0; c < 4; ++c) zacc[t][c] = (f32x4){0,0,0,0};
    }
#pragma unroll
    for (int kk = 0; kk < 8; ++kk) {
        f16x8 pb  = pnH[(size_t)(kk * 4 + w) * 64 + lane];
        f16x8 gb0 = Gh[(size_t)(kk * 16 + w +  0) * 64 + lane];
        f16x8 gb1 = Gh[(size_t)(kk * 16 + w +  4) * 64 + lane];
        f16x8 gb2 = Gh[(size_t)(kk * 16 + w +  8) * 64 + lane];
        f16x8 gb3 = Gh[(size_t)(kk * 16 + w + 12) * 64 + lane];
#pragma unroll
        for (int t = 0; t < RT; ++t) {
            f16x8 a = outH[(t * 8 + kk) * 64 + lane];
            lacc[t]    = __builtin_amdgcn_mfma_f32_16x16x32_f16(a, pb,  lacc[t],    0, 0, 0);
            zacc[t][0] = __builtin_amdgcn_mfma_f32_16x16x32_f16(a, gb0, zacc[t][0], 0, 0, 0);
            zacc[t][1] = __builtin_amdgcn_mfma_f32_16x16x32_f16(a, gb1, zacc[t][1], 0, 0, 0);
            zacc[t][2] = __builtin_amdgcn_mfma_f32_16x16x32_f16(a, gb2, zacc[t][2], 0, 0, 0);
            zacc[t][3] = __builtin_amdgcn_mfma_f32_16x16x32_f16(a, gb3, zacc[t][3], 0, 0, 0);
        }
    }
#pragma unroll
    for (int t = 0; t < RT; ++t)
#pragma unroll
        for (int i = 0; i < 4; ++i) {
            int r = t * 16 + quad * 4 + i;
            attL[r * LDA + w * 16 + m] = lacc[t][i] * scaleL[r];
        }
    __syncthreads();

    // ---- softmax over 64 proxies (no max: cosine logits <= 1) ----
#pragma unroll
    for (int t = 0; t < RT; ++t)
#pragma unroll
        for (int i = 0; i < 4; ++i) {
            int r = t * 16 + 4 * w + i;
            float e = __expf(attL[r * LDA + lane]);
            float s = waveReduceSum(e);
            attL[r * LDA + lane] = e / s;
        }
    __syncthreads();

    // ---- q = att@proxy ; z -= att@PG ----
    f32x4 qacc[RT][4];
#pragma unroll
    for (int t = 0; t < RT; ++t)
#pragma unroll
        for (int c = 0; c < 4; ++c) qacc[t][c] = (f32x4){0,0,0,0};
#pragma unroll
    for (int kk = 0; kk < 2; ++kk) {
        f16x8 a[RT];
#pragma unroll
        for (int t = 0; t < RT; ++t) {
            const float4* ap = (const float4*)&attL[(t * 16 + m) * LDA + kk * 32 + quad * 8];
            float4 x = ap[0], y = ap[1];
            a[t][0]=(_Float16)x.x; a[t][1]=(_Float16)x.y; a[t][2]=(_Float16)x.z; a[t][3]=(_Float16)x.w;
            a[t][4]=(_Float16)y.x; a[t][5]=(_Float16)y.y; a[t][6]=(_Float16)y.z; a[t][7]=(_Float16)y.w;
        }
#pragma unroll
        for (int cgi = 0; cgi < 4; ++cgi) {
            int cg = w + 4 * cgi;
            f16x8 bx = pxH[(size_t)(kk * 16 + cg) * 64 + lane];
            f16x8 bg = pgH[(size_t)(kk * 16 + cg) * 64 + lane];
#pragma unroll
            for (int t = 0; t < RT; ++t) {
                qacc[t][cgi] = __builtin_amdgcn_mfma_f32_16x16x32_f16(a[t], bx, qacc[t][cgi], 0, 0, 0);
                zacc[t][cgi] = __builtin_amdgcn_mfma_f32_16x16x32_f16(a[t], bg, zacc[t][cgi], 0, 0, 0);
            }
        }
    }

    // ---- epilogue: ov from LDS (f16), gate, store ----
    const _Float16* outHs = (const _Float16*)outH;
#pragma unroll
    for (int t = 0; t < RT; ++t) {
        if ((int)row0 + t * 16 >= N) break;
#pragma unroll
        for (int cgi = 0; cgi < 4; ++cgi) {
            int cg = w + 4 * cgi;
            int c = cg * 16 + m;
            int kkc = cg >> 1;
            int qc = ((cg & 1) << 1) | (m >> 3);
            int j = m & 7;
#pragma unroll
            for (int i = 0; i < 4; ++i) {
                int r15 = quad * 4 + i;
                float ov = (float)outHs[(((t * 8 + kkc) * 64 + qc * 16 + r15) << 3) + j];
                float gate = 1.f / (1.f + __expf(-zacc[t][cgi][i]));
                size_t n = row0 + t * 16 + r15;
                out[n * OUTC + c] = ov - (1.f - gate) * qacc[t][cgi][i];
            }
        }
    }
}

extern "C" void kernel_launch(void* const* d_in, const int* in_sizes, int n_in,
                              void* d_out, int out_size, void* d_ws, size_t ws_size,
                              hipStream_t stream) {
    const float* features   = (const float*)d_in[0];
    const float* rel_emb    = (const float*)d_in[1];
    const float* sparse_val = (const float*)d_in[2];
    const float* attn       = (const float*)d_in[3];
    const float* proxy      = (const float*)d_in[4];
    const float* gateK      = (const float*)d_in[5];
    const int*   adj        = (const int*)d_in[6];
    const int*   sidx       = (const int*)d_in[7];
    const int*   neigh      = (const int*)d_in[9];
    float* out = (float*)d_out;

    char* ws = (char*)d_ws;
    size_t off = 0;
    auto alloc = [&](size_t bytes) -> void* {
        void* p = ws + off;
        off += (bytes + 255) & ~(size_t)255;
        return p;
    };
    _Float16* relnormH = (_Float16*)alloc((size_t)R * F * 2);
    float*    dotr     = (float*)alloc((size_t)R * 2 * 4);
    f16x8*    Gh       = (f16x8*)alloc((size_t)128 * 64 * 16);
    f16x8*    pnH      = (f16x8*)alloc((size_t)32 * 64 * 16);
    f16x8*    pxH      = (f16x8*)alloc((size_t)32 * 64 * 16);
    f16x8*    pgH      = (f16x8*)alloc((size_t)32 * 64 * 16);
    _Float16* featsH   = (_Float16*)alloc((size_t)N * F * 2);
    int*      nstart   = (int*)alloc((size_t)N * 4);
    int*      nend     = (int*)alloc((size_t)N * 4);
    int4*     epack    = (int4*)alloc((size_t)E * 16);
    _Float16* nf0      = (_Float16*)alloc((size_t)N * F * 2);
    _Float16* nf1      = (_Float16*)alloc((size_t)N * F * 2);

    prep1<<<B_FEATSH + B_REL + B_SEG + B_FRAG, 256, 0, stream>>>(
        features, rel_emb, attn, proxy, gateK, adj, sidx, sparse_val,
        featsH, relnormH, dotr, nstart, nend, epack, Gh, pnH, pxH, pgH);
    node_aggregate<<<N / 4, 256, 0, stream>>>(featsH, relnormH, dotr, epack,
                                              nstart, nend, nf0, nf1);
    proxy_gate<<<(N + RT * 16 - 1) / (RT * 16), 256, 0, stream>>>(
        featsH, nf0, nf1, neigh, pnH, pxH, Gh, pgH, out);
}

// Round 7
// 178.864 us; speedup vs baseline: 1.1312x; 1.1312x over previous
//
#include <hip/hip_runtime.h>
#include <math.h>

constexpr int N  = 50000;
constexpr int E  = 400000;
constexpr int R  = 1000;
constexpr int K1 = 1000;
constexpr int F  = 128;
constexpr int OUTC = 256;
constexpr int P  = 64;

typedef _Float16 f16x8 __attribute__((ext_vector_type(8)));
typedef _Float16 f16x4 __attribute__((ext_vector_type(4)));
typedef _Float16 f16x2 __attribute__((ext_vector_type(2)));
typedef float f32x4 __attribute__((ext_vector_type(4)));

#if __has_builtin(__builtin_amdgcn_fdot2)
#define FDOT2(a, b, c) __builtin_amdgcn_fdot2((a), (b), (c), false)
#else
#define FDOT2(a, b, c) fmaf((float)(a)[0], (float)(b)[0], fmaf((float)(a)[1], (float)(b)[1], (c)))
#endif

__device__ inline float waveReduceSum(float v) {
#pragma unroll
    for (int m = 32; m >= 1; m >>= 1) v += __shfl_xor(v, m, 64);
    return v;
}

// ---------------- prep_a: featsh | relprep | seg+edgepack | pscale | PGf ---------
constexpr int B_FEATSH = 6250;   // N*F/4 / 256
constexpr int B_REL    = 250;    // R/4 (wave per relation)
constexpr int B_SEG    = 1563;
constexpr int B_PSC    = 16;     // P/4 (wave per proxy row)
constexpr int B_PGF    = 64;     // one block per proxy row, coalesced over cols

__global__ __launch_bounds__(256) void prep_a(
        const float* __restrict__ feats, const float* __restrict__ rel_emb,
        const float* __restrict__ attn,  const float* __restrict__ proxy,
        const float* __restrict__ G,     const int* __restrict__ adj,
        const int* __restrict__ sidx,    const float* __restrict__ val,
        _Float16* __restrict__ featsH,   _Float16* __restrict__ relnormH,
        float* __restrict__ dotr, int* __restrict__ nstart, int* __restrict__ nend,
        int4* __restrict__ epack, float* __restrict__ pscale,
        float* __restrict__ PGf) {
    int b = blockIdx.x, tid = threadIdx.x;
    if (b < B_FEATSH) {
        int idx = b * 256 + tid;
        float4 x = ((const float4*)feats)[idx];
        f16x4 h;
        h[0] = (_Float16)x.x; h[1] = (_Float16)x.y;
        h[2] = (_Float16)x.z; h[3] = (_Float16)x.w;
        ((f16x4*)featsH)[idx] = h;
    } else if (b < B_FEATSH + B_REL) {
        int r = (b - B_FEATSH) * 4 + (tid >> 6);
        int lane = tid & 63;
        float2 v  = ((const float2*)(rel_emb + (size_t)r * F))[lane];
        float2 a0 = ((const float2*)attn)[lane];
        float2 a1 = ((const float2*)attn)[64 + lane];
        float ss = waveReduceSum(v.x * v.x + v.y * v.y);
        float d0 = waveReduceSum(v.x * a0.x + v.y * a0.y);
        float d1 = waveReduceSum(v.x * a1.x + v.y * a1.y);
        float sc = rsqrtf(fmaxf(ss, 1e-12f));
        f16x2 h; h[0] = (_Float16)(v.x * sc); h[1] = (_Float16)(v.y * sc);
        ((f16x2*)(relnormH + (size_t)r * F))[lane] = h;
        if (lane == 0) { dotr[2 * r] = d0; dotr[2 * r + 1] = d1; }
    } else if (b < B_FEATSH + B_REL + B_SEG) {
        int e = (b - B_FEATSH - B_REL) * 256 + tid;
        if (e < E) {
            int2 a2 = ((const int2*)adj)[e];
            int row = a2.x;
            int rel = ((const int2*)sidx)[e].y;
            epack[e] = make_int4(a2.y, rel, __float_as_int(val[e]), 0);
            int prev = (e > 0) ? ((const int2*)adj)[e - 1].x : -1;
            if (prev != row) {
                nstart[row] = e;
                for (int rr = prev + 1; rr < row; ++rr) { nstart[rr] = e; nend[rr] = e; }
            }
            if (e == E - 1) {
                nend[row] = E;
                for (int rr = row + 1; rr < N; ++rr) { nstart[rr] = E; nend[rr] = E; }
            } else if (((const int2*)adj)[e + 1].x != row) {
                nend[row] = e + 1;
            }
        }
    } else if (b < B_FEATSH + B_REL + B_SEG + B_PSC) {
        int j = (b - B_FEATSH - B_REL - B_SEG) * 4 + (tid >> 6);
        int lane = tid & 63;
        float4 p = ((const float4*)(proxy + (size_t)j * OUTC))[lane];
        float ss = waveReduceSum(p.x * p.x + p.y * p.y + p.z * p.z + p.w * p.w);
        if (lane == 0) pscale[j] = rsqrtf(fmaxf(ss, 1e-12f));
    } else {
        // PGf[p][c] = sum_k proxy[p][k] * G[k][c]  (coalesced over c)
        int p = b - (B_FEATSH + B_REL + B_SEG + B_PSC);
        int c = tid;
        float s = 0.f;
        for (int k = 0; k < OUTC; ++k)
            s = fmaf(proxy[(size_t)p * OUTC + k], G[(size_t)k * OUTC + c], s);
        PGf[(size_t)p * OUTC + c] = s;
    }
}

// ---------------- node_aggregate + fragprep (merged grids) -----------------------
// B-frag 16x16x32: lane L holds B[k = kk*32 + (L>>4)*8 + j][n = base + (L&15)]
constexpr int NB_NODE = N / 4;   // 12500
constexpr int NB_FRAG = 56;      // 224 64-lane units / 4

__global__ __launch_bounds__(256) void node_frag(
        const _Float16* __restrict__ featsH,
        const _Float16* __restrict__ relnormH,
        const float* __restrict__ dotr,
        const int4* __restrict__ epack,
        const int* __restrict__ nstart,
        const int* __restrict__ nend,
        const float* __restrict__ G,
        const float* __restrict__ proxy,
        const float* __restrict__ pscale,
        const float* __restrict__ PGf,
        _Float16* __restrict__ nf0,
        _Float16* __restrict__ nf1,
        f16x8* __restrict__ Gh, f16x8* __restrict__ pnH,
        f16x8* __restrict__ pxH, f16x8* __restrict__ pgH) {
    if (blockIdx.x >= NB_NODE) {
        // ---- fragprep ----
        int u = (blockIdx.x - NB_NODE) * 4 + (threadIdx.x >> 6);  // 0..223
        int L = threadIdx.x & 63;
        int q = L >> 4, m = L & 15;
        f16x8 h;
        if (u < 128) {                               // Gh: G (256x256)
            int kk = u >> 4, cg = u & 15;
            int n = cg * 16 + m;
#pragma unroll
            for (int j = 0; j < 8; ++j)
                h[j] = (_Float16)G[(size_t)(kk * 32 + q * 8 + j) * OUTC + n];
            Gh[(size_t)u * 64 + L] = h;
        } else if (u < 160) {                        // pnH: l2n(proxy)^T (256x64)
            int idx = u - 128;
            int kk = idx >> 2, w = idx & 3;
            int n = w * 16 + m;
            float sc = pscale[n];
#pragma unroll
            for (int j = 0; j < 8; ++j)
                h[j] = (_Float16)(proxy[(size_t)n * OUTC + kk * 32 + q * 8 + j] * sc);
            pnH[(size_t)idx * 64 + L] = h;
        } else if (u < 192) {                        // pxH: proxy (64x256)
            int idx = u - 160;
            int kk = idx >> 4, cg = idx & 15;
            int n = cg * 16 + m;
#pragma unroll
            for (int j = 0; j < 8; ++j)
                h[j] = (_Float16)proxy[(size_t)(kk * 32 + q * 8 + j) * OUTC + n];
            pxH[(size_t)idx * 64 + L] = h;
        } else {                                     // pgH: -(proxy@G) from PGf
            int idx = u - 192;
            int kk = idx >> 4, cg = idx & 15;
            int n = cg * 16 + m;
#pragma unroll
            for (int j = 0; j < 8; ++j)
                h[j] = (_Float16)(-PGf[(size_t)(kk * 32 + q * 8 + j) * OUTC + n]);
            pgH[(size_t)idx * 64 + L] = h;
        }
        return;
    }
    // ---- node aggregation: single pass, normalize at end ----
    int n = blockIdx.x * 4 + (threadIdx.x >> 6);
    int lane = threadIdx.x & 63;
    int g = lane >> 4, gl = lane & 15;
    int start = nstart[n], end = nend[n];
    float A0[8], A1[8];
#pragma unroll
    for (int j = 0; j < 8; ++j) { A0[j] = 0.f; A1[j] = 0.f; }
    float s0 = 0.f, s1 = 0.f;
    for (int e = start + g; e < end; e += 8) {
        int eB = e + 4;
        bool hasB = (eB < end);
        int eBc = hasB ? eB : e;
        int4 mA = epack[e], mB = epack[eBc];
        float2 drA = ((const float2*)dotr)[mA.y];
        float2 drB = ((const float2*)dotr)[mB.y];
        float vA = __int_as_float(mA.z), vB = __int_as_float(mB.z);
        float wA0 = __expf(vA * drA.x), wA1 = __expf(vA * drA.y);
        float wB0 = hasB ? __expf(vB * drB.x) : 0.f;
        float wB1 = hasB ? __expf(vB * drB.y) : 0.f;
        s0 += wA0 + wB0; s1 += wA1 + wB1;
        f16x8 fAv = ((const f16x8*)(featsH   + (size_t)mA.x * F))[gl];
        f16x8 rAv = ((const f16x8*)(relnormH + (size_t)mA.y * F))[gl];
        f16x8 fBv = ((const f16x8*)(featsH   + (size_t)mB.x * F))[gl];
        f16x8 rBv = ((const f16x8*)(relnormH + (size_t)mB.y * F))[gl];
        const f16x2* fA2 = (const f16x2*)&fAv;
        const f16x2* rA2 = (const f16x2*)&rAv;
        const f16x2* fB2 = (const f16x2*)&fBv;
        const f16x2* rB2 = (const f16x2*)&rBv;
        float pdA = 0.f, pdB = 0.f;
#pragma unroll
        for (int j = 0; j < 4; ++j) {
            pdA = FDOT2(fA2[j], rA2[j], pdA);
            pdB = FDOT2(fB2[j], rB2[j], pdB);
        }
        pdA += __shfl_xor(pdA, 1, 64); pdB += __shfl_xor(pdB, 1, 64);
        pdA += __shfl_xor(pdA, 2, 64); pdB += __shfl_xor(pdB, 2, 64);
        pdA += __shfl_xor(pdA, 4, 64); pdB += __shfl_xor(pdB, 4, 64);
        pdA += __shfl_xor(pdA, 8, 64); pdB += __shfl_xor(pdB, 8, 64);
        _Float16 tAh = (_Float16)(2.f * pdA), tBh = (_Float16)(2.f * pdB);
        f16x2 tA2; tA2[0] = tAh; tA2[1] = tAh;
        f16x2 tB2; tB2[0] = tBh; tB2[1] = tBh;
#pragma unroll
        for (int j = 0; j < 4; ++j) {
            f16x2 rxA = fA2[j] - tA2 * rA2[j];
            f16x2 rxB = fB2[j] - tB2 * rB2[j];
            float x0 = (float)rxA[0], x1 = (float)rxA[1];
            float y0 = (float)rxB[0], y1 = (float)rxB[1];
            A0[2*j]   = fmaf(wA0, x0, A0[2*j]);   A0[2*j]   = fmaf(wB0, y0, A0[2*j]);
            A0[2*j+1] = fmaf(wA0, x1, A0[2*j+1]); A0[2*j+1] = fmaf(wB0, y1, A0[2*j+1]);
            A1[2*j]   = fmaf(wA1, x0, A1[2*j]);   A1[2*j]   = fmaf(wB1, y0, A1[2*j]);
            A1[2*j+1] = fmaf(wA1, x1, A1[2*j+1]); A1[2*j+1] = fmaf(wB1, y1, A1[2*j+1]);
        }
    }
#pragma unroll
    for (int j = 0; j < 8; ++j) {
        A0[j] += __shfl_xor(A0[j], 16, 64); A0[j] += __shfl_xor(A0[j], 32, 64);
        A1[j] += __shfl_xor(A1[j], 16, 64); A1[j] += __shfl_xor(A1[j], 32, 64);
    }
    s0 += __shfl_xor(s0, 16, 64); s0 += __shfl_xor(s0, 32, 64);
    s1 += __shfl_xor(s1, 16, 64); s1 += __shfl_xor(s1, 32, 64);
    float i0 = (s0 > 0.f) ? 1.f / s0 : 0.f;
    float i1 = (s1 > 0.f) ? 1.f / s1 : 0.f;
    if (g == 0) {
        f16x8 h0, h1;
#pragma unroll
        for (int j = 0; j < 8; ++j) {
            h0[j] = (_Float16)(A0[j] * i0);
            h1[j] = (_Float16)(A1[j] * i1);
        }
        ((f16x8*)(nf0 + (size_t)n * F))[gl] = h0;
        ((f16x8*)(nf1 + (size_t)n * F))[gl] = h1;
    }
}

// ---------------- F: fused build + proxy attention + gate, 32 rows/block ----------
// z = out@G - att@(proxy@G);  q = att@proxy;  final = out - (1-sigmoid(z))*q
constexpr int RT = 2;   // 16-row tiles per block
__global__ __launch_bounds__(256, 4) void proxy_gate(
        const _Float16* __restrict__ featsH,
        const _Float16* __restrict__ nf0,
        const _Float16* __restrict__ nf1,
        const int* __restrict__ neigh,
        const f16x8* __restrict__ pnH,
        const f16x8* __restrict__ pxH,
        const f16x8* __restrict__ Gh,
        const f16x8* __restrict__ pgH,
        float* __restrict__ out) {
    constexpr int LDA = 68;
    __shared__ __align__(16) f16x8 outH[RT * 8 * 64];     // 16 KB, A-frag order
    __shared__ __align__(16) float attL[RT * 16 * LDA];   // 8.7 KB
    __shared__ float scaleL[RT * 16];
    int tid = threadIdx.x;
    int w = tid >> 6, lane = tid & 63;
    int quad = lane >> 4, m = lane & 15;
    size_t row0 = (size_t)blockIdx.x * (RT * 16);

    // ---- build tiles -> f16 A-frags + row 1/norm ----
    {
        int bm = tid >> 4, gl = tid & 15;
#pragma unroll
        for (int t = 0; t < RT; ++t) {
            int n = (int)row0 + t * 16 + bm;
            float ss;
            f16x8 h1, h2;
            if (n < N) {
                ss = 0.f;
                h1 = ((const f16x8*)(featsH + (size_t)n * F))[gl];
#pragma unroll
                for (int j = 0; j < 8; ++j) { float x = (float)h1[j]; ss += x * x; }
                int sel = (n < K1) ? neigh[n] : n;
                f16x8 a  = ((const f16x8*)(nf0 + (size_t)n   * F))[gl];
                f16x8 b2 = ((const f16x8*)(nf1 + (size_t)sel * F))[gl];
#pragma unroll
                for (int j = 0; j < 8; ++j) {
                    float v = 0.5f * ((float)a[j] + (float)b2[j]);
                    h2[j] = (_Float16)v;
                    ss += v * v;
                }
            } else {
#pragma unroll
                for (int j = 0; j < 8; ++j) { h1[j] = (_Float16)0.f; h2[j] = (_Float16)0.f; }
                ss = 1.f;
            }
            outH[(t * 8 +     (gl >> 2)) * 64 + (gl & 3) * 16 + bm] = h1;
            outH[(t * 8 + 4 + (gl >> 2)) * 64 + (gl & 3) * 16 + bm] = h2;
            ss += __shfl_xor(ss, 1, 64); ss += __shfl_xor(ss, 2, 64);
            ss += __shfl_xor(ss, 4, 64); ss += __shfl_xor(ss, 8, 64);
            if (gl == 0) scaleL[t * 16 + bm] = rsqrtf(fmaxf(ss, 1e-12f));
        }
    }
    __syncthreads();

    // ---- logits (wave w: proxies 16w..) + z partial = out@G (cols cg=w+4i) ----
    f32x4 lacc[RT];
    f32x4 zacc[RT][4];
#pragma unroll
    for (int t = 0; t < RT; ++t) {
        lacc[t] = (f32x4){0,0,0,0};
#pragma unroll
        for (int c = 0; c < 4; ++c) zacc[t][c] = (f32x4){0,0,0,0};
    }
#pragma unroll
    for (int kk = 0; kk < 8; ++kk) {
        f16x8 pb  = pnH[(size_t)(kk * 4 + w) * 64 + lane];
        f16x8 gb0 = Gh[(size_t)(kk * 16 + w +  0) * 64 + lane];
        f16x8 gb1 = Gh[(size_t)(kk * 16 + w +  4) * 64 + lane];
        f16x8 gb2 = Gh[(size_t)(kk * 16 + w +  8) * 64 + lane];
        f16x8 gb3 = Gh[(size_t)(kk * 16 + w + 12) * 64 + lane];
#pragma unroll
        for (int t = 0; t < RT; ++t) {
            f16x8 a = outH[(t * 8 + kk) * 64 + lane];
            lacc[t]    = __builtin_amdgcn_mfma_f32_16x16x32_f16(a, pb,  lacc[t],    0, 0, 0);
            zacc[t][0] = __builtin_amdgcn_mfma_f32_16x16x32_f16(a, gb0, zacc[t][0], 0, 0, 0);
            zacc[t][1] = __builtin_amdgcn_mfma_f32_16x16x32_f16(a, gb1, zacc[t][1], 0, 0, 0);
            zacc[t][2] = __builtin_amdgcn_mfma_f32_16x16x32_f16(a, gb2, zacc[t][2], 0, 0, 0);
            zacc[t][3] = __builtin_amdgcn_mfma_f32_16x16x32_f16(a, gb3, zacc[t][3], 0, 0, 0);
        }
    }
#pragma unroll
    for (int t = 0; t < RT; ++t)
#pragma unroll
        for (int i = 0; i < 4; ++i) {
            int r = t * 16 + quad * 4 + i;
            attL[r * LDA + w * 16 + m] = lacc[t][i] * scaleL[r];
        }
    __syncthreads();

    // ---- softmax over 64 proxies (no max: cosine logits <= 1) ----
#pragma unroll
    for (int t = 0; t < RT; ++t)
#pragma unroll
        for (int i = 0; i < 4; ++i) {
            int r = t * 16 + 4 * w + i;
            float e = __expf(attL[r * LDA + lane]);
            float s = waveReduceSum(e);
            attL[r * LDA + lane] = e / s;
        }
    __syncthreads();

    // ---- q = att@proxy ; z -= att@PG ----
    f32x4 qacc[RT][4];
#pragma unroll
    for (int t = 0; t < RT; ++t)
#pragma unroll
        for (int c = 0; c < 4; ++c) qacc[t][c] = (f32x4){0,0,0,0};
#pragma unroll
    for (int kk = 0; kk < 2; ++kk) {
        f16x8 a[RT];
#pragma unroll
        for (int t = 0; t < RT; ++t) {
            const float4* ap = (const float4*)&attL[(t * 16 + m) * LDA + kk * 32 + quad * 8];
            float4 x = ap[0], y = ap[1];
            a[t][0]=(_Float16)x.x; a[t][1]=(_Float16)x.y; a[t][2]=(_Float16)x.z; a[t][3]=(_Float16)x.w;
            a[t][4]=(_Float16)y.x; a[t][5]=(_Float16)y.y; a[t][6]=(_Float16)y.z; a[t][7]=(_Float16)y.w;
        }
#pragma unroll
        for (int cgi = 0; cgi < 4; ++cgi) {
            int cg = w + 4 * cgi;
            f16x8 bx = pxH[(size_t)(kk * 16 + cg) * 64 + lane];
            f16x8 bg = pgH[(size_t)(kk * 16 + cg) * 64 + lane];
#pragma unroll
            for (int t = 0; t < RT; ++t) {
                qacc[t][cgi] = __builtin_amdgcn_mfma_f32_16x16x32_f16(a[t], bx, qacc[t][cgi], 0, 0, 0);
                zacc[t][cgi] = __builtin_amdgcn_mfma_f32_16x16x32_f16(a[t], bg, zacc[t][cgi], 0, 0, 0);
            }
        }
    }

    // ---- epilogue: ov from LDS (f16), gate, store ----
    const _Float16* outHs = (const _Float16*)outH;
#pragma unroll
    for (int t = 0; t < RT; ++t) {
        if ((int)row0 + t * 16 >= N) break;
#pragma unroll
        for (int cgi = 0; cgi < 4; ++cgi) {
            int cg = w + 4 * cgi;
            int c = cg * 16 + m;
            int kkc = cg >> 1;
            int qc = ((cg & 1) << 1) | (m >> 3);
            int j = m & 7;
#pragma unroll
            for (int i = 0; i < 4; ++i) {
                int r15 = quad * 4 + i;
                float ov = (float)outHs[(((t * 8 + kkc) * 64 + qc * 16 + r15) << 3) + j];
                float gate = 1.f / (1.f + __expf(-zacc[t][cgi][i]));
                size_t n = row0 + t * 16 + r15;
                out[n * OUTC + c] = ov - (1.f - gate) * qacc[t][cgi][i];
            }
        }
    }
}

extern "C" void kernel_launch(void* const* d_in, const int* in_sizes, int n_in,
                              void* d_out, int out_size, void* d_ws, size_t ws_size,
                              hipStream_t stream) {
    const float* features   = (const float*)d_in[0];
    const float* rel_emb    = (const float*)d_in[1];
    const float* sparse_val = (const float*)d_in[2];
    const float* attn       = (const float*)d_in[3];
    const float* proxy      = (const float*)d_in[4];
    const float* gateK      = (const float*)d_in[5];
    const int*   adj        = (const int*)d_in[6];
    const int*   sidx       = (const int*)d_in[7];
    const int*   neigh      = (const int*)d_in[9];
    float* out = (float*)d_out;

    char* ws = (char*)d_ws;
    size_t off = 0;
    auto alloc = [&](size_t bytes) -> void* {
        void* p = ws + off;
        off += (bytes + 255) & ~(size_t)255;
        return p;
    };
    _Float16* relnormH = (_Float16*)alloc((size_t)R * F * 2);
    float*    dotr     = (float*)alloc((size_t)R * 2 * 4);
    float*    pscale   = (float*)alloc((size_t)P * 4);
    float*    PGf      = (float*)alloc((size_t)P * OUTC * 4);
    f16x8*    Gh       = (f16x8*)alloc((size_t)128 * 64 * 16);
    f16x8*    pnH      = (f16x8*)alloc((size_t)32 * 64 * 16);
    f16x8*    pxH      = (f16x8*)alloc((size_t)32 * 64 * 16);
    f16x8*    pgH      = (f16x8*)alloc((size_t)32 * 64 * 16);
    _Float16* featsH   = (_Float16*)alloc((size_t)N * F * 2);
    int*      nstart   = (int*)alloc((size_t)N * 4);
    int*      nend     = (int*)alloc((size_t)N * 4);
    int4*     epack    = (int4*)alloc((size_t)E * 16);
    _Float16* nf0      = (_Float16*)alloc((size_t)N * F * 2);
    _Float16* nf1      = (_Float16*)alloc((size_t)N * F * 2);

    prep_a<<<B_FEATSH + B_REL + B_SEG + B_PSC + B_PGF, 256, 0, stream>>>(
        features, rel_emb, attn, proxy, gateK, adj, sidx, sparse_val,
        featsH, relnormH, dotr, nstart, nend, epack, pscale, PGf);
    node_frag<<<NB_NODE + NB_FRAG, 256, 0, stream>>>(
        featsH, relnormH, dotr, epack, nstart, nend, gateK, proxy, pscale, PGf,
        nf0, nf1, Gh, pnH, pxH, pgH);
    proxy_gate<<<(N + RT * 16 - 1) / (RT * 16), 256, 0, stream>>>(
        featsH, nf0, nf1, neigh, pnH, pxH, Gh, pgH, out);
}